// Round 15
// baseline (76.372 us; speedup 1.0000x reference)
//
#include <hip/hip_runtime.h>

// PPO loss fused pipeline for MI355X (gfx950).
// R15: 128 rows/block (512 blocks x 512 thr, wave = 128x32, acc[8][2]) to
// HALVE the dominant memory term: the per-block K x N weight-panel read
// (400 KB/block; was 1024 blocks x 400KB = 410 MB through L2/L3 -- invisible
// in FETCH_SIZE, explains why replays with 0 HBM run identically and why 4
// different 64-row structures all converged at ~66us). Weight traffic now
// 205 MB. B fragment-major global (R10+), A K-step LDS dbuf (R9/R13 swizzle),
// smH [128][256] with A-dbuf overlay -> 64KB LDS, 2 blocks/CU, 16 waves/CU.

#define TT 65536

typedef float f32x4 __attribute__((ext_vector_type(4)));
typedef __bf16 bf16x8 __attribute__((ext_vector_type(8)));
typedef unsigned short u16x8 __attribute__((ext_vector_type(8)));
typedef unsigned int u32x4 __attribute__((ext_vector_type(4)));

__device__ __forceinline__ unsigned short f2bf(float f) {
    unsigned int u = __float_as_uint(f);
    unsigned int r = (u + 0x7fffu + ((u >> 16) & 1u)) >> 16;
    return (unsigned short)r;
}

// hw packed fp32->bf16 (RTNE)
__device__ __forceinline__ unsigned int cvt_pk_bf16(float a, float b) {
    unsigned int r;
    asm("v_cvt_pk_bf16_f32 %0, %1, %2" : "=v"(r) : "v"(a), "v"(b));
    return r;
}

// branch-free tanh: 1 - 2/(e^{2x}+1)
__device__ __forceinline__ float fast_tanh(float x) {
    float e = __expf(2.0f * x);
    return fmaf(-2.0f, __builtin_amdgcn_rcpf(e + 1.0f), 1.0f);
}

// ---------------- GAE affine suffix scan ----------------
__device__ __forceinline__ void suffix_scan256(float* sC, float* sD, int i) {
    float c = sC[i], d = sD[i];
#pragma unroll
    for (int s = 1; s < 256; s <<= 1) {
        float c2 = 1.0f, d2 = 0.0f;
        if (i + s < 256) { c2 = sC[i + s]; d2 = sD[i + s]; }
        __syncthreads();
        d = d + c * d2;
        c = c * c2;
        sC[i] = c; sD[i] = d;
        __syncthreads();
    }
}

__device__ __forceinline__ void gae_cd(const float* rewards, const float* terms,
                                       const float* values, int t, float* c, float* d) {
    float nt = 1.0f - terms[t];
    float nv = (t + 1 < TT) ? values[t + 1] : 0.0f;
    *d = rewards[t] + 0.99f * nv * nt - values[t];
    *c = 0.99f * 0.95f * nt;
}

// ---------------- fused prep + gae1 ----------------
// Fragment-major layouts (verified R10-R14):
//   frag (kt, nt): elem ((kt*16+nt)*64 + l)*8 + e = W[k = kt*32+(l>>4)*8+e][col = nt*16+(l&15)]
__global__ void k_prep_gae1(const float* __restrict__ W1, const float* __restrict__ W2,
                            const float* __restrict__ Wa, const float* __restrict__ Wc,
                            unsigned short* __restrict__ W1Tf, unsigned short* __restrict__ W2Tf,
                            unsigned short* __restrict__ Wavf,
                            const float* __restrict__ rewards, const float* __restrict__ terms,
                            const float* __restrict__ values, float* __restrict__ aggC,
                            float* __restrict__ aggD) {
    if (blockIdx.x < 800) {
        int idx = blockIdx.x * 256 + threadIdx.x;
        if (idx < 131072) {
            int col = idx & 255, k = idx >> 8;            // coalesced read of W1[k][:]
            int kt = k >> 5, lh = (k & 31) >> 3, e = k & 7;
            int nt = col >> 4, cl = col & 15;
            W1Tf[(((kt * 16 + nt) * 64) + lh * 16 + cl) * 8 + e] = f2bf(W1[k * 256 + col]);
        } else if (idx < 196608) {
            int i = idx - 131072;
            int col = i & 255, k = i >> 8;
            int kt = k >> 5, lh = (k & 31) >> 3, e = k & 7;
            int nt = col >> 4, cl = col & 15;
            W2Tf[(((kt * 16 + nt) * 64) + lh * 16 + cl) * 8 + e] = f2bf(W2[k * 256 + col]);
        } else if (idx < 204800) {
            int i = idx - 196608;                          // [0,4096) Wa, [4096,8192) Wc
            if (i < 4096) {
                int a = i & 15, k = i >> 4;
                int kt = k >> 5, lh = (k & 31) >> 3, e = k & 7;
                Wavf[(((kt * 2 + 0) * 64) + lh * 16 + a) * 8 + e] = f2bf(Wa[k * 16 + a]);
            } else {
                int j = i - 4096;
                int a = j & 15, k = j >> 4;
                int kt = k >> 5, lh = (k & 31) >> 3, e = k & 7;
                float v = (a == 0) ? Wc[k] : 0.0f;
                Wavf[(((kt * 2 + 1) * 64) + lh * 16 + a) * 8 + e] = f2bf(v);
            }
        }
        return;
    }
    __shared__ float sC[256], sD[256];
    int i = threadIdx.x;
    int b = blockIdx.x - 800;
    int t = b * 256 + i;
    float c, d;
    gae_cd(rewards, terms, values, t, &c, &d);
    sC[i] = c; sD[i] = d;
    __syncthreads();
    suffix_scan256(sC, sD, i);
    if (i == 0) { aggC[b] = sC[0]; aggD[b] = sD[0]; }
}

// ---------------- gae3: carry + adv/ret + per-block sum partials ----------------
__global__ void k_gae3(const float* __restrict__ rewards, const float* __restrict__ terms,
                       const float* __restrict__ values, const float* __restrict__ aggC,
                       const float* __restrict__ aggD, float* __restrict__ adv,
                       float* __restrict__ ret, float* __restrict__ sumP) {
    __shared__ float sC[256], sD[256];
    int i = threadIdx.x, b = blockIdx.x;
    sC[i] = aggC[i]; sD[i] = aggD[i];
    __syncthreads();
    suffix_scan256(sC, sD, i);
    float carry = (b < 255) ? sD[b + 1] : 0.0f;
    __syncthreads();

    int t = b * 256 + i;
    float c, d;
    gae_cd(rewards, terms, values, t, &c, &d);
    sC[i] = c; sD[i] = d;
    __syncthreads();
    suffix_scan256(sC, sD, i);
    float a = sD[i] + sC[i] * carry;
    adv[t] = a;
    ret[t] = a + values[t];
    __syncthreads();
    sC[i] = a; sD[i] = a * a;
    __syncthreads();
#pragma unroll
    for (int s = 128; s > 0; s >>= 1) {
        if (i < s) { sC[i] += sC[i + s]; sD[i] += sD[i + s]; }
        __syncthreads();
    }
    if (i == 0) { sumP[2 * b] = sC[0]; sumP[2 * b + 1] = sD[0]; }
}

// ---------------- fused MLP + heads + loss (128 rows/block, 8 waves) ----------------
// Wave wid owns output cols [wid*32, +32); acc[8][2] (64 VGPR), rows 0..127.
// LDS 64KB: smH [128][256] bf16; A-dbuf (2 x [128][32] = 16KB) overlays smH
// (A-dbuf dead before epilogue1 writes smH). Stats reduce uses same region first.
// A tile swizzle: 16B slot' = slot ^ ((row>>1)&3).  smH: elem' = elem ^ ((row&7)<<3).
__global__ __launch_bounds__(512, 2) void k_mlp(
    const float* __restrict__ obs, const int* __restrict__ actions,
    const float* __restrict__ logprobs, const float* __restrict__ values,
    const float* __restrict__ b1, const float* __restrict__ b2,
    const float* __restrict__ ba, const float* __restrict__ bc,
    const unsigned short* __restrict__ W1Tf, const unsigned short* __restrict__ W2Tf,
    const unsigned short* __restrict__ Wavf, const float* __restrict__ adv,
    const float* __restrict__ ret, const float* __restrict__ sumP,
    float* __restrict__ lossP) {
    __shared__ __align__(16) unsigned char SM[65536];
    unsigned short* smA = (unsigned short*)SM;          // 2 x 4096 elems (GEMM1 only)
    unsigned short* smH = (unsigned short*)SM;          // [128][256] after GEMM1

    const int tid = threadIdx.x;
    const int wid = tid >> 6;
    const int lane = tid & 63;
    const int cl = lane & 15;
    const int gg = lane >> 4;
    const int bm0 = blockIdx.x * 128;

    // ---- adv stats (folds gae4): 512-float reduce in LDS ----
    float meanA, rstdA;
    {
        float* red = (float*)SM;
        if (tid < 256) { red[tid] = sumP[2 * tid]; red[256 + tid] = sumP[2 * tid + 1]; }
        __syncthreads();
#pragma unroll
        for (int s = 128; s > 0; s >>= 1) {
            if (tid < s) { red[tid] += red[tid + s]; red[256 + tid] += red[256 + tid + s]; }
            __syncthreads();
        }
        meanA = red[0] * (1.0f / TT);
        float var = red[256] * (1.0f / TT) - meanA * meanA;
        rstdA = 1.0f / (sqrtf(fmaxf(var, 0.0f)) + 1e-8f);
        __syncthreads();   // red reads done before staging overwrites
    }

    float b1v[2], b2v[2];
#pragma unroll
    for (int n = 0; n < 2; ++n) {
        int c = wid * 32 + n * 16 + cl;
        b1v[n] = b1[c];
        b2v[n] = b2[c];
    }
    const float bav = ba[cl];
    const float bc0 = bc[0];

    // A staging map: thread -> one swizzled 8-elem slot of a [128][32] tile
    const int arow = tid >> 2;                  // 0..127
    const int aslot = tid & 3;                  // 0..3
    const int adst = arow * 32 + ((aslot ^ ((arow >> 1) & 3)) << 3);
    const float* aSrc = obs + (size_t)(bm0 + arow) * 512 + aslot * 8;

    f32x4 acc[8][2];
#pragma unroll
    for (int m = 0; m < 8; ++m)
#pragma unroll
        for (int n = 0; n < 2; ++n) acc[m][n] = (f32x4){0.f, 0.f, 0.f, 0.f};

    auto cvtWriteA = [&](const float4& f0, const float4& f1, int buf) {
        u32x4 pk;
        pk[0] = cvt_pk_bf16(f0.x, f0.y);
        pk[1] = cvt_pk_bf16(f0.z, f0.w);
        pk[2] = cvt_pk_bf16(f1.x, f1.y);
        pk[3] = cvt_pk_bf16(f1.z, f1.w);
        *(u32x4*)&smA[buf * 4096 + adst] = pk;
    };

    // ---------------- GEMM1: hidden1 = tanh(obs @ W1 + b1), K=512, 16 tiles ----------------
    // A: LDS dbuf (1 barrier/iter). B: fragment-major global (L2-warm), 2 frags/wave.
    {
        const unsigned short* bBase = W1Tf + ((size_t)(wid * 2) << 9) + lane * 8;
        float4 a0 = *(const float4*)(aSrc);
        float4 a1 = *(const float4*)(aSrc + 4);
        cvtWriteA(a0, a1, 0);
        __syncthreads();
#pragma unroll
        for (int t = 0; t < 16; ++t) {
            if (t < 15) {
                a0 = *(const float4*)(aSrc + (t + 1) * 32);
                a1 = *(const float4*)(aSrc + (t + 1) * 32 + 4);
            }
            bf16x8 av[8], bv[2];
#pragma unroll
            for (int n = 0; n < 2; ++n)
                bv[n] = *(const bf16x8*)(bBase + ((size_t)(t * 16 + n) << 9));
#pragma unroll
            for (int m = 0; m < 8; ++m) {
                int ra = m * 16 + cl;
                av[m] = *(const bf16x8*)&smA[(t & 1) * 4096 + ra * 32 + ((gg ^ ((ra >> 1) & 3)) << 3)];
            }
#pragma unroll
            for (int m = 0; m < 8; ++m)
#pragma unroll
                for (int n = 0; n < 2; ++n)
                    acc[m][n] = __builtin_amdgcn_mfma_f32_16x16x32_bf16(av[m], bv[n], acc[m][n], 0, 0, 0);
            if (t < 15) cvtWriteA(a0, a1, (t + 1) & 1);
            __syncthreads();
        }
    }

    // epilogue 1: tanh -> smH (swizzled; A-dbuf dead), reset acc
#pragma unroll
    for (int m = 0; m < 8; ++m)
#pragma unroll
        for (int n = 0; n < 2; ++n)
#pragma unroll
            for (int j = 0; j < 4; ++j) {
                int r = m * 16 + gg * 4 + j;
                int c = wid * 32 + n * 16 + cl;
                smH[r * 256 + (c ^ ((r & 7) << 3))] = f2bf(fast_tanh(acc[m][n][j] + b1v[n]));
                acc[m][n][j] = 0.0f;
            }
    __syncthreads();   // hidden1 visible; smH read-only until epilogue2

    // ---------------- GEMM2: K=256, 8 tiles — NO barriers ----------------
    {
        const unsigned short* bBase = W2Tf + ((size_t)(wid * 2) << 9) + lane * 8;
#pragma unroll
        for (int t = 0; t < 8; ++t) {
            bf16x8 av[8], bv[2];
#pragma unroll
            for (int n = 0; n < 2; ++n)
                bv[n] = *(const bf16x8*)(bBase + ((size_t)(t * 16 + n) << 9));
#pragma unroll
            for (int m = 0; m < 8; ++m) {
                int ra = m * 16 + cl;
                av[m] = *(const bf16x8*)&smH[ra * 256 + ((t * 32 + gg * 8) ^ ((ra & 7) << 3))];
            }
#pragma unroll
            for (int m = 0; m < 8; ++m)
#pragma unroll
                for (int n = 0; n < 2; ++n)
                    acc[m][n] = __builtin_amdgcn_mfma_f32_16x16x32_bf16(av[m], bv[n], acc[m][n], 0, 0, 0);
        }
    }

    __syncthreads();   // all GEMM2 smH reads done -> safe to overwrite in place

    // epilogue 2: hidden -> smH
#pragma unroll
    for (int m = 0; m < 8; ++m)
#pragma unroll
        for (int n = 0; n < 2; ++n)
#pragma unroll
            for (int j = 0; j < 4; ++j) {
                int r = m * 16 + gg * 4 + j;
                int c = wid * 32 + n * 16 + cl;
                smH[r * 256 + (c ^ ((r & 7) << 3))] = f2bf(fast_tanh(acc[m][n][j] + b2v[n]));
            }
    __syncthreads();   // hidden2 visible

    // ---------------- heads + loss: wave wid owns rows [wid*16, +16) ----------------
    float lsum = 0.0f;
    {
        f32x4 acc_a = {0.f, 0.f, 0.f, 0.f}, acc_v = {0.f, 0.f, 0.f, 0.f};
        const unsigned short* wBase = Wavf + lane * 8;
#pragma unroll
        for (int kk = 0; kk < 8; ++kk) {
            int r = wid * 16 + cl;
            bf16x8 av = *(const bf16x8*)&smH[r * 256 + ((kk * 32 + gg * 8) ^ ((r & 7) << 3))];
            bf16x8 bva = *(const bf16x8*)(wBase + ((size_t)(kk * 2) << 9));
            bf16x8 bvv = *(const bf16x8*)(wBase + ((size_t)(kk * 2 + 1) << 9));
            acc_a = __builtin_amdgcn_mfma_f32_16x16x32_bf16(av, bva, acc_a, 0, 0, 0);
            acc_v = __builtin_amdgcn_mfma_f32_16x16x32_bf16(av, bvv, acc_v, 0, 0, 0);
        }

        const int t0 = bm0 + wid * 16;
#pragma unroll
        for (int j = 0; j < 4; ++j) {
            int t = t0 + gg * 4 + j;
            float lg = acc_a[j] + bav;
            float mx = lg;
#pragma unroll
            for (int dd = 1; dd < 16; dd <<= 1) mx = fmaxf(mx, __shfl_xor(mx, dd));
            float ex = __expf(lg - mx);
            float se = ex;
#pragma unroll
            for (int dd = 1; dd < 16; dd <<= 1) se += __shfl_xor(se, dd);
            float ls = __logf(se);
            float lp = lg - mx - ls;
            float pl = __expf(lp) * lp;
            float ent = pl;
#pragma unroll
            for (int dd = 1; dd < 16; dd <<= 1) ent += __shfl_xor(ent, dd);
            ent = -ent;
            int act = actions[t];
            float newlp = __shfl(lp, (lane & 48) | act);
            float val = __shfl(acc_v[j], lane & 48) + bc0;

            float lpo = logprobs[t];
            float at = (adv[t] - meanA) * rstdA;
            float rt = ret[t];
            float vo = values[t];
            float ratio = __expf(newlp - lpo);
            float rcl = fminf(fmaxf(ratio, 0.8f), 1.2f);
            float pg = fmaxf(-at * ratio, -at * rcl);
            float vcl = vo + fminf(fmaxf(val - vo, -0.2f), 0.2f);
            float dv = val - rt, dvc = vcl - rt;
            float vl = fmaxf(dv * dv, dvc * dvc);
            if (cl == 0) lsum += pg - 0.01f * ent + 0.25f * vl;
        }
        lsum += __shfl_xor(lsum, 16);
        lsum += __shfl_xor(lsum, 32);
    }
    __syncthreads();   // all smH reads done; reuse SM for final reduce
    float* red2 = (float*)SM;
    if (lane == 0) red2[wid] = lsum;
    __syncthreads();
    if (tid == 0) {
        float s = 0.0f;
#pragma unroll
        for (int w = 0; w < 8; ++w) s += red2[w];
        lossP[blockIdx.x] = s;
    }
}

__global__ void k_final(const float* __restrict__ lossP, float* __restrict__ out) {
    __shared__ float s[256];
    int i = threadIdx.x;
    s[i] = lossP[i] + lossP[i + 256];
    __syncthreads();
#pragma unroll
    for (int st = 128; st > 0; st >>= 1) {
        if (i < st) s[i] += s[i + st];
        __syncthreads();
    }
    if (i == 0) out[0] = s[0] * (1.0f / TT);
}

extern "C" void kernel_launch(void* const* d_in, const int* in_sizes, int n_in,
                              void* d_out, int out_size, void* d_ws, size_t ws_size,
                              hipStream_t stream) {
    const float* obs      = (const float*)d_in[0];
    const int*   actions  = (const int*)d_in[1];
    const float* logprobs = (const float*)d_in[2];
    const float* rewards  = (const float*)d_in[3];
    const float* terms    = (const float*)d_in[4];
    const float* values   = (const float*)d_in[5];
    const float* W1 = (const float*)d_in[6];
    const float* b1 = (const float*)d_in[7];
    const float* W2 = (const float*)d_in[8];
    const float* b2 = (const float*)d_in[9];
    const float* Wa = (const float*)d_in[10];
    const float* ba = (const float*)d_in[11];
    const float* Wc = (const float*)d_in[12];
    const float* bc = (const float*)d_in[13];

    char* ws = (char*)d_ws;
    unsigned short* W1Tf = (unsigned short*)(ws + 0);        // 262144 B
    unsigned short* W2Tf = (unsigned short*)(ws + 262144);   // 131072 B
    unsigned short* Wavf = (unsigned short*)(ws + 393216);   // 16384 B
    float* advp  = (float*)(ws + 409600);                    // 262144 B
    float* retp  = (float*)(ws + 671744);                    // 262144 B
    float* aggC  = (float*)(ws + 933888);                    // 1024 B
    float* aggD  = (float*)(ws + 934912);                    // 1024 B
    float* sumP  = (float*)(ws + 936960);                    // 2048 B
    float* lossP = (float*)(ws + 939072);                    // 2048 B

    k_prep_gae1<<<1056, 256, 0, stream>>>(W1, W2, Wa, Wc, W1Tf, W2Tf, Wavf,
                                          rewards, terms, values, aggC, aggD);
    k_gae3<<<256, 256, 0, stream>>>(rewards, terms, values, aggC, aggD, advp, retp, sumP);
    k_mlp<<<512, 512, 0, stream>>>(obs, actions, logprobs, values, b1, b2, ba, bc,
                                   W1Tf, W2Tf, Wavf, advp, retp, sumP, lossP);
    k_final<<<1, 256, 0, stream>>>(lossP, (float*)d_out);
}